// Round 9
// baseline (51.338 us; speedup 1.0000x reference)
//
#include <hip/hip_runtime.h>
#include <hip/hip_bf16.h>
#include <math.h>

constexpr int B = 4, C = 64, H = 128, W = 128, K = 9, O = 64;
constexpr int HXW = H * W;

typedef _Float16 half8 __attribute__((ext_vector_type(8)));
typedef float f32x4 __attribute__((ext_vector_type(4)));

// ---------------- fallback path (fp32, proven round 1) ----------------
__global__ void wt_kernel(const float* __restrict__ weight, float* __restrict__ wt) {
    int idx = blockIdx.x * 256 + threadIdx.x;
    if (idx >= K * C * O) return;
    int o = idx & 63;
    int c = (idx >> 6) & 63;
    int k = idx >> 12;
    wt[idx] = weight[(o * C + c) * K + k];
}

__global__ __launch_bounds__(256) void mdcn_nchw(
        const float* __restrict__ x, const float* __restrict__ offset,
        const float* __restrict__ mask, const float* __restrict__ wt,
        const float* __restrict__ bias, float* __restrict__ out) {
    int pid = blockIdx.x * 256 + threadIdx.x;
    int b = pid >> 14;
    int hw = pid & (HXW - 1);
    int h = hw >> 7;
    int w = hw & 127;
    float acc[O];
#pragma unroll
    for (int o = 0; o < O; ++o) acc[o] = bias[o];
#pragma unroll 1
    for (int k = 0; k < K; ++k) {
        float offy = offset[((size_t)(b * 2 * K + 2 * k)) * HXW + hw];
        float offx = offset[((size_t)(b * 2 * K + 2 * k + 1)) * HXW + hw];
        float m    = mask[((size_t)(b * K + k)) * HXW + hw];
        float sy = (float)(h - 1 + k / 3) + offy;
        float sx = (float)(w - 1 + k % 3) + offx;
        float y0f = floorf(sy), x0f = floorf(sx);
        float wy = sy - y0f, wx = sx - x0f;
        int y0 = (int)y0f, x0 = (int)x0f;
        int y1 = y0 + 1, x1 = x0 + 1;
        bool vy0 = (y0 >= 0) & (y0 < H), vy1 = (y1 >= 0) & (y1 < H);
        bool vx0 = (x0 >= 0) & (x0 < W), vx1 = (x1 >= 0) & (x1 < W);
        float w00 = (vy0 & vx0) ? (1.0f - wy) * (1.0f - wx) * m : 0.0f;
        float w01 = (vy0 & vx1) ? (1.0f - wy) * wx * m : 0.0f;
        float w10 = (vy1 & vx0) ? wy * (1.0f - wx) * m : 0.0f;
        float w11 = (vy1 & vx1) ? wy * wx * m : 0.0f;
        int y0c = min(max(y0, 0), H - 1), y1c = min(max(y1, 0), H - 1);
        int x0c = min(max(x0, 0), W - 1), x1c = min(max(x1, 0), W - 1);
        const float* p00 = x + (size_t)b * C * HXW + y0c * W + x0c;
        const float* p01 = x + (size_t)b * C * HXW + y0c * W + x1c;
        const float* p10 = x + (size_t)b * C * HXW + y1c * W + x0c;
        const float* p11 = x + (size_t)b * C * HXW + y1c * W + x1c;
        const float* wk = wt + k * C * O;
#pragma unroll 1
        for (int c0 = 0; c0 < C; c0 += 4) {
            float v[4];
#pragma unroll
            for (int j = 0; j < 4; ++j) {
                size_t cs = (size_t)(c0 + j) * HXW;
                v[j] = w00 * p00[cs] + w01 * p01[cs] + w10 * p10[cs] + w11 * p11[cs];
            }
            const float* wr = wk + c0 * O;
#pragma unroll
            for (int j = 0; j < 4; ++j)
#pragma unroll
                for (int o = 0; o < O; ++o) acc[o] = fmaf(wr[j * O + o], v[j], acc[o]);
        }
    }
#pragma unroll
    for (int o = 0; o < O; ++o) out[((size_t)(b * O + o)) * HXW + hw] = acc[o];
}

// ---------------- prep: xht NHWC fp16 + lane-packed fp16 weights ----------------
constexpr int XT_BLOCKS = B * HXW / 128;   // 512
__global__ __launch_bounds__(256) void prep_kernel(
        const float* __restrict__ x, const float* __restrict__ weight,
        _Float16* __restrict__ xht, _Float16* __restrict__ wth) {
    int bid = blockIdx.x;
    if (bid < XT_BLOCKS) {
        __shared__ float lds[128 * 65];
        int t = threadIdx.x;
        int P = bid * 128;
        int b = P >> 14;
        int hw0 = P & (HXW - 1);
        int px = t & 127;
        int hf = t >> 7;
        const float* src = x + (size_t)b * C * HXW + hw0 + px;
#pragma unroll
        for (int cc = 0; cc < 32; ++cc) {
            int ch = hf * 32 + cc;
            lds[px * 65 + ch] = src[(size_t)ch * HXW];
        }
        __syncthreads();
        _Float16* dst = xht + ((size_t)b * HXW + hw0 + px) * 64 + hf * 32;
        const float* row = lds + px * 65 + hf * 32;
#pragma unroll
        for (int j = 0; j < 4; ++j) {
            half8 pk;
#pragma unroll
            for (int e = 0; e < 8; ++e) pk[e] = (_Float16)row[j * 8 + e];
            *(half8*)(dst + j * 8) = pk;
        }
    } else {
        int idx = (bid - XT_BLOCKS) * 256 + threadIdx.x;
        if (idx < K * O * C) {
            int e = idx & 7;
            int lane = (idx >> 3) & 63;
            int s = (idx >> 9) & 7;
            int k = idx >> 12;
            int ml = lane & 15, kg = lane >> 4;
            int nf = s & 3, ks = s >> 2;
            int o = nf * 16 + ml;
            int c = ks * 32 + kg * 8 + e;
            wth[idx] = (_Float16)weight[(o * C + c) * K + k];
        }
    }
}

// ---------------- main: LDS-resident weights, direct-fragment gather, f16 MFMA ----
// 512 blocks x 512 threads (8 waves = one 128-px image row per block).
// Wave = 16 px x 64 out. Lane (ml,kg): px = ml, chans ks*32+kg*8..+8 -> combine
// writes MFMA A-fragments DIRECTLY in registers (no A-LDS, no barriers in k-loop).
// Weights: all 72 KB staged to LDS once per block; B-frags via ds_read_b128.
// slab = bid & 7 -> (batch, half-image) keeps each XCD's gathers in its L2.
__global__ __launch_bounds__(512, 4) void mdcn_f16(
        const _Float16* __restrict__ xht,  // [B][H][W][64] fp16
        const float* __restrict__ offset,  // [B][2K][H][W]
        const float* __restrict__ mask,    // [B][K][H][W]
        const _Float16* __restrict__ wth,  // [K][8][64][8] fp16 lane-packed
        const float* __restrict__ bias,    // [O]
        float* __restrict__ out) {         // [B][O][H][W]
    __shared__ _Float16 Wlds[K * 8 * 64 * 8];   // 73728 B

    int bid = blockIdx.x;
    int slab = bid & 7;
    int within = bid >> 3;                  // 0..63
    int tid = threadIdx.x;
    int lane = tid & 63;
    int wid = tid >> 6;                     // 0..7
    int ml = lane & 15, kg = lane >> 4;
    int b = slab >> 1;
    int row = (slab & 1) * 64 + within;     // image row
    int hwrow = row * 128;
    int wvpx = wid * 16;                    // wave's first pixel in the row
    int h = row;
    int hwpx = hwrow + wvpx + ml;           // this lane's pixel (dup x4 over kg)
    int wpx = wvpx + ml;                    // image x of this lane's pixel

    // ---- stage weights to LDS (one-time) ----
#pragma unroll
    for (int j = 0; j < 9; ++j) {
        int idx = tid + j * 512;            // 16-B chunk id, 4608 total
        *(half8*)(Wlds + idx * 8) = *(const half8*)(wth + idx * 8);
    }
    __syncthreads();

    f32x4 acc[4];
#pragma unroll
    for (int nf = 0; nf < 4; ++nf) {
        float bv = bias[nf * 16 + ml];
        acc[nf] = (f32x4){bv, bv, bv, bv};
    }

    const _Float16* xb = xht + (size_t)b * HXW * 64;
    const float* offb = offset + (size_t)b * 2 * K * HXW;
    const float* mskb = mask + (size_t)b * K * HXW;

    // prologue: offsets for tap 0
    float oy = offb[hwpx];
    float ox = offb[(size_t)HXW + hwpx];
    float mm = mskb[hwpx];

#pragma unroll 1
    for (int k = 0; k < K; ++k) {
        int ky = k / 3 - 1, kx = k % 3 - 1;

        // ---- phase 2: corner weights + record indices (pure VALU) ----
        float sy = (float)(h + ky) + oy;
        float sx = (float)(wpx + kx) + ox;
        float y0f = floorf(sy), x0f = floorf(sx);
        float wy = sy - y0f, wx = sx - x0f;
        int y0 = (int)y0f, x0 = (int)x0f;
        int y1 = y0 + 1, x1 = x0 + 1;
        bool vy0 = (y0 >= 0) & (y0 < H), vy1 = (y1 >= 0) & (y1 < H);
        bool vx0 = (x0 >= 0) & (x0 < W), vx1 = (x1 >= 0) & (x1 < W);
        float w00 = (vy0 & vx0) ? (1.0f - wy) * (1.0f - wx) * mm : 0.0f;
        float w01 = (vy0 & vx1) ? (1.0f - wy) * wx * mm : 0.0f;
        float w10 = (vy1 & vx0) ? wy * (1.0f - wx) * mm : 0.0f;
        float w11 = (vy1 & vx1) ? wy * wx * mm : 0.0f;
        int y0c = min(max(y0, 0), H - 1), y1c = min(max(y1, 0), H - 1);
        int x0c = min(max(x0, 0), W - 1), x1c = min(max(x1, 0), W - 1);
        int r00 = y0c * W + x0c, r01 = y0c * W + x1c;
        int r10 = y1c * W + x0c, r11 = y1c * W + x1c;
        int chb = kg * 8;                   // this lane's channel base within a half

        // ---- phase 3: issue ALL 8 gathers back-to-back ----
        half8 c00[2], c01[2], c10[2], c11[2];
#pragma unroll
        for (int ks = 0; ks < 2; ++ks) {
            int co = ks * 32 + chb;
            c00[ks] = *(const half8*)(xb + r00 * 64 + co);
            c01[ks] = *(const half8*)(xb + r01 * 64 + co);
            c10[ks] = *(const half8*)(xb + r10 * 64 + co);
            c11[ks] = *(const half8*)(xb + r11 * 64 + co);
        }

        // ---- phase 3.5: prefetch next tap's offsets (hidden under gathers) ----
        float oy2 = 0.f, ox2 = 0.f, mm2 = 0.f;
        if (k + 1 < K) {
            oy2 = offb[(size_t)(2 * k + 2) * HXW + hwpx];
            ox2 = offb[(size_t)(2 * k + 3) * HXW + hwpx];
            mm2 = mskb[(size_t)(k + 1) * HXW + hwpx];
        }
        __builtin_amdgcn_sched_barrier(0);   // pin: loads above, consumers below

        // ---- phase 4: packed-fp16 combine -> A-fragments in registers ----
        _Float16 h00 = (_Float16)w00, h01 = (_Float16)w01;
        _Float16 h10 = (_Float16)w10, h11 = (_Float16)w11;
        half8 af[2];
#pragma unroll
        for (int ks = 0; ks < 2; ++ks)
            af[ks] = c00[ks] * h00 + c01[ks] * h01 + c10[ks] * h10 + c11[ks] * h11;

        // ---- phase 5: MFMA, B-frags from LDS ----
#pragma unroll
        for (int ks = 0; ks < 2; ++ks) {
#pragma unroll
            for (int nf = 0; nf < 4; ++nf) {
                half8 bfr = *(const half8*)(Wlds + ((k * 8 + ks * 4 + nf) * 64 + lane) * 8);
                acc[nf] = __builtin_amdgcn_mfma_f32_16x16x32_f16(af[ks], bfr, acc[nf], 0, 0, 0);
            }
        }

        oy = oy2; ox = ox2; mm = mm2;
    }

    // ---- store: D row(px) = kg*4 + reg, col(o) = nf*16 + ml ----
    int hwb = hwrow + wvpx + kg * 4;
#pragma unroll
    for (int nf = 0; nf < 4; ++nf) {
        size_t ob = ((size_t)(b * O + nf * 16 + ml)) * HXW + hwb;
        *(float4*)(out + ob) = __builtin_bit_cast(float4, acc[nf]);
    }
}

extern "C" void kernel_launch(void* const* d_in, const int* in_sizes, int n_in,
                              void* d_out, int out_size, void* d_ws, size_t ws_size,
                              hipStream_t stream) {
    const float* x      = (const float*)d_in[0];
    const float* offset = (const float*)d_in[1];
    const float* mask   = (const float*)d_in[2];
    const float* weight = (const float*)d_in[3];
    const float* bias   = (const float*)d_in[4];
    float* out = (float*)d_out;

    _Float16* wth = (_Float16*)d_ws;                              // 73728 B
    _Float16* xht = (_Float16*)((char*)d_ws + 73728);             // 8.39 MB
    size_t need = 73728 + (size_t)B * HXW * 64 * sizeof(_Float16);

    if (ws_size >= need) {
        int wth_blocks = (K * O * C + 255) / 256;                 // 144
        prep_kernel<<<XT_BLOCKS + wth_blocks, 256, 0, stream>>>(x, weight, xht, wth);
        mdcn_f16<<<512, 512, 0, stream>>>(xht, offset, mask, wth, bias, out);
    } else {
        float* wt = (float*)d_ws;                                 // 147456 B (fallback)
        wt_kernel<<<(K * C * O + 255) / 256, 256, 0, stream>>>(weight, wt);
        mdcn_nchw<<<(B * HXW) / 256, 256, 0, stream>>>(x, offset, mask, wt, bias, out);
    }
}

// Round 10
// 36.316 us; speedup vs baseline: 1.4136x; 1.4136x over previous
//
#include <hip/hip_runtime.h>
#include <hip/hip_bf16.h>
#include <math.h>

constexpr int B = 4, C = 64, H = 128, W = 128, K = 9, O = 64;
constexpr int HXW = H * W;

typedef _Float16 half8 __attribute__((ext_vector_type(8)));
typedef float f32x4 __attribute__((ext_vector_type(4)));

// ---------------- fallback path (fp32, proven round 1) ----------------
__global__ void wt_kernel(const float* __restrict__ weight, float* __restrict__ wt) {
    int idx = blockIdx.x * 256 + threadIdx.x;
    if (idx >= K * C * O) return;
    int o = idx & 63;
    int c = (idx >> 6) & 63;
    int k = idx >> 12;
    wt[idx] = weight[(o * C + c) * K + k];
}

__global__ __launch_bounds__(256) void mdcn_nchw(
        const float* __restrict__ x, const float* __restrict__ offset,
        const float* __restrict__ mask, const float* __restrict__ wt,
        const float* __restrict__ bias, float* __restrict__ out) {
    int pid = blockIdx.x * 256 + threadIdx.x;
    int b = pid >> 14;
    int hw = pid & (HXW - 1);
    int h = hw >> 7;
    int w = hw & 127;
    float acc[O];
#pragma unroll
    for (int o = 0; o < O; ++o) acc[o] = bias[o];
#pragma unroll 1
    for (int k = 0; k < K; ++k) {
        float offy = offset[((size_t)(b * 2 * K + 2 * k)) * HXW + hw];
        float offx = offset[((size_t)(b * 2 * K + 2 * k + 1)) * HXW + hw];
        float m    = mask[((size_t)(b * K + k)) * HXW + hw];
        float sy = (float)(h - 1 + k / 3) + offy;
        float sx = (float)(w - 1 + k % 3) + offx;
        float y0f = floorf(sy), x0f = floorf(sx);
        float wy = sy - y0f, wx = sx - x0f;
        int y0 = (int)y0f, x0 = (int)x0f;
        int y1 = y0 + 1, x1 = x0 + 1;
        bool vy0 = (y0 >= 0) & (y0 < H), vy1 = (y1 >= 0) & (y1 < H);
        bool vx0 = (x0 >= 0) & (x0 < W), vx1 = (x1 >= 0) & (x1 < W);
        float w00 = (vy0 & vx0) ? (1.0f - wy) * (1.0f - wx) * m : 0.0f;
        float w01 = (vy0 & vx1) ? (1.0f - wy) * wx * m : 0.0f;
        float w10 = (vy1 & vx0) ? wy * (1.0f - wx) * m : 0.0f;
        float w11 = (vy1 & vx1) ? wy * wx * m : 0.0f;
        int y0c = min(max(y0, 0), H - 1), y1c = min(max(y1, 0), H - 1);
        int x0c = min(max(x0, 0), W - 1), x1c = min(max(x1, 0), W - 1);
        const float* p00 = x + (size_t)b * C * HXW + y0c * W + x0c;
        const float* p01 = x + (size_t)b * C * HXW + y0c * W + x1c;
        const float* p10 = x + (size_t)b * C * HXW + y1c * W + x0c;
        const float* p11 = x + (size_t)b * C * HXW + y1c * W + x1c;
        const float* wk = wt + k * C * O;
#pragma unroll 1
        for (int c0 = 0; c0 < C; c0 += 4) {
            float v[4];
#pragma unroll
            for (int j = 0; j < 4; ++j) {
                size_t cs = (size_t)(c0 + j) * HXW;
                v[j] = w00 * p00[cs] + w01 * p01[cs] + w10 * p10[cs] + w11 * p11[cs];
            }
            const float* wr = wk + c0 * O;
#pragma unroll
            for (int j = 0; j < 4; ++j)
#pragma unroll
                for (int o = 0; o < O; ++o) acc[o] = fmaf(wr[j * O + o], v[j], acc[o]);
        }
    }
#pragma unroll
    for (int o = 0; o < O; ++o) out[((size_t)(b * O + o)) * HXW + hw] = acc[o];
}

// ---------------- prep: xht NHWC fp16 + lane-packed fp16 weights ----------------
constexpr int XT_BLOCKS = B * HXW / 128;   // 512
__global__ __launch_bounds__(256) void prep_kernel(
        const float* __restrict__ x, const float* __restrict__ weight,
        _Float16* __restrict__ xht, _Float16* __restrict__ wth) {
    int bid = blockIdx.x;
    if (bid < XT_BLOCKS) {
        __shared__ float lds[128 * 65];
        int t = threadIdx.x;
        int P = bid * 128;
        int b = P >> 14;
        int hw0 = P & (HXW - 1);
        int px = t & 127;
        int hf = t >> 7;
        const float* src = x + (size_t)b * C * HXW + hw0 + px;
#pragma unroll
        for (int cc = 0; cc < 32; ++cc) {
            int ch = hf * 32 + cc;
            lds[px * 65 + ch] = src[(size_t)ch * HXW];
        }
        __syncthreads();
        _Float16* dst = xht + ((size_t)b * HXW + hw0 + px) * 64 + hf * 32;
        const float* row = lds + px * 65 + hf * 32;
#pragma unroll
        for (int j = 0; j < 4; ++j) {
            half8 pk;
#pragma unroll
            for (int e = 0; e < 8; ++e) pk[e] = (_Float16)row[j * 8 + e];
            *(half8*)(dst + j * 8) = pk;
        }
    } else {
        int idx = (bid - XT_BLOCKS) * 256 + threadIdx.x;
        if (idx < K * O * C) {
            int e = idx & 7;
            int lane = (idx >> 3) & 63;
            int s = (idx >> 9) & 7;
            int k = idx >> 12;
            int ml = lane & 15, kg = lane >> 4;
            int nf = s & 3, ks = s >> 2;
            int o = nf * 16 + ml;
            int c = ks * 32 + kg * 8 + e;
            wth[idx] = (_Float16)weight[(o * C + c) * K + k];
        }
    }
}

// ---------------- main: minimal-touch gather + LDS weights + f16 MFMA ----------------
// 256 blocks x 1024 threads (16 waves); block = 256 px (2 image rows).
// Wave = 16 px x 64 out. Gather: lane (p8=lane>>3, ch8=lane&7) -> one instr = 8 full
// 128-B pixel records = 8 lines (touch-minimal). A-tile: wave-private LDS, XOR swizzle,
// no barriers in k-loop. Weights: 72 KB staged to LDS once; B-frags via ds_read_b128.
// slab = bid & 7 -> (batch, half-image) keeps each XCD's gathers in its own L2.
__global__ __launch_bounds__(1024, 1) void mdcn_f16(
        const _Float16* __restrict__ xht,  // [B][H][W][64] fp16
        const float* __restrict__ offset,  // [B][2K][H][W]
        const float* __restrict__ mask,    // [B][K][H][W]
        const _Float16* __restrict__ wth,  // [K][8][64][8] fp16 lane-packed
        const float* __restrict__ bias,    // [O]
        float* __restrict__ out) {         // [B][O][H][W]
    __shared__ _Float16 Wlds[K * 8 * 64 * 8];     // 73728 B
    __shared__ _Float16 Alds[16][16 * 64];        // 16 x 2 KB, wave-private

    int bid = blockIdx.x;
    int slab = bid & 7;                    // (batch, half-image) -> XCD
    int within = bid >> 3;                 // 0..31
    int tid = threadIdx.x;
    int lane = tid & 63;
    int wid = tid >> 6;                    // 0..15
    int ml = lane & 15, kg = lane >> 4;
    int p8 = lane >> 3, ch8 = lane & 7;
    int b = slab >> 1;
    int hwblk = (slab & 1) * 8192 + within * 256;  // block's first pixel (row-pair)
    int h = (hwblk >> 7) + (wid >> 3);     // this wave's image row
    int wbase = (wid & 7) * 16;            // wave's first x within the row
    int hwwave = h * 128 + wbase;          // wave's first pixel index
    _Float16* Aw = &Alds[wid][0];

    // ---- stage weights to LDS (one-time) ----
#pragma unroll
    for (int j = 0; j < 5; ++j) {
        int idx = tid + j * 1024;          // 16-B chunks, 4608 total
        if (idx < K * 8 * 64) *(half8*)(Wlds + idx * 8) = *(const half8*)(wth + idx * 8);
    }
    __syncthreads();

    f32x4 acc[4];
#pragma unroll
    for (int nf = 0; nf < 4; ++nf) {
        float bv = bias[nf * 16 + ml];
        acc[nf] = (f32x4){bv, bv, bv, bv};
    }

    const _Float16* xb = xht + (size_t)b * HXW * 64;
    const float* offb = offset + (size_t)b * 2 * K * HXW;
    const float* mskb = mask + (size_t)b * K * HXW;

    // prologue: offsets for tap 0 (lane's pixel for gather = hwwave + g*8+p8)
    float oy[2], ox[2], mm[2];
#pragma unroll
    for (int g = 0; g < 2; ++g) {
        int hw = hwwave + g * 8 + p8;
        oy[g] = offb[hw];
        ox[g] = offb[(size_t)HXW + hw];
        mm[g] = mskb[hw];
    }

#pragma unroll 1
    for (int k = 0; k < K; ++k) {
        int ky = k / 3 - 1, kx = k % 3 - 1;

        // ---- phase 2: corner weights + record indices (pure VALU) ----
        float w00[2], w01[2], w10[2], w11[2];
        int r00[2], r01[2], r10[2], r11[2];
#pragma unroll
        for (int g = 0; g < 2; ++g) {
            int pl = g * 8 + p8;
            int w = wbase + pl;
            float sy = (float)(h + ky) + oy[g];
            float sx = (float)(w + kx) + ox[g];
            float y0f = floorf(sy), x0f = floorf(sx);
            float wy = sy - y0f, wx = sx - x0f;
            int y0 = (int)y0f, x0 = (int)x0f;
            int y1 = y0 + 1, x1 = x0 + 1;
            bool vy0 = (y0 >= 0) & (y0 < H), vy1 = (y1 >= 0) & (y1 < H);
            bool vx0 = (x0 >= 0) & (x0 < W), vx1 = (x1 >= 0) & (x1 < W);
            float m = mm[g];
            w00[g] = (vy0 & vx0) ? (1.0f - wy) * (1.0f - wx) * m : 0.0f;
            w01[g] = (vy0 & vx1) ? (1.0f - wy) * wx * m : 0.0f;
            w10[g] = (vy1 & vx0) ? wy * (1.0f - wx) * m : 0.0f;
            w11[g] = (vy1 & vx1) ? wy * wx * m : 0.0f;
            int y0c = min(max(y0, 0), H - 1), y1c = min(max(y1, 0), H - 1);
            int x0c = min(max(x0, 0), W - 1), x1c = min(max(x1, 0), W - 1);
            r00[g] = y0c * W + x0c;
            r01[g] = y0c * W + x1c;
            r10[g] = y1c * W + x0c;
            r11[g] = y1c * W + x1c;
        }

        // ---- phase 3: issue ALL 8 gathers back-to-back (8 full records each) ----
        half8 c00[2], c01[2], c10[2], c11[2];
#pragma unroll
        for (int g = 0; g < 2; ++g) {
            c00[g] = *(const half8*)(xb + r00[g] * 64 + ch8 * 8);
            c01[g] = *(const half8*)(xb + r01[g] * 64 + ch8 * 8);
            c10[g] = *(const half8*)(xb + r10[g] * 64 + ch8 * 8);
            c11[g] = *(const half8*)(xb + r11[g] * 64 + ch8 * 8);
        }

        // ---- phase 3.5: prefetch next tap's offsets (hidden under gathers) ----
        float oy2[2], ox2[2], mm2[2];
        if (k + 1 < K) {
#pragma unroll
            for (int g = 0; g < 2; ++g) {
                int hw = hwwave + g * 8 + p8;
                oy2[g] = offb[(size_t)(2 * k + 2) * HXW + hw];
                ox2[g] = offb[(size_t)(2 * k + 3) * HXW + hw];
                mm2[g] = mskb[(size_t)(k + 1) * HXW + hw];
            }
        }
        __builtin_amdgcn_sched_barrier(0);   // pin: loads above, consumers below

        // ---- phase 4: packed-fp16 combine -> wave-private LDS A-tile ----
#pragma unroll
        for (int g = 0; g < 2; ++g) {
            int pl = g * 8 + p8;
            _Float16 h00 = (_Float16)w00[g], h01 = (_Float16)w01[g];
            _Float16 h10 = (_Float16)w10[g], h11 = (_Float16)w11[g];
            half8 pk = c00[g] * h00 + c01[g] * h01 + c10[g] * h10 + c11[g] * h11;
            *(half8*)(Aw + pl * 64 + ((ch8 ^ (pl & 7)) * 8)) = pk;
        }

        // ---- phase 5: MFMA; B-frags from LDS weights, A-frags from A-tile ----
#pragma unroll
        for (int ks = 0; ks < 2; ++ks) {
            half8 af = *(const half8*)(Aw + ml * 64 + (((ks * 4 + kg) ^ (ml & 7)) * 8));
#pragma unroll
            for (int nf = 0; nf < 4; ++nf) {
                half8 bfr = *(const half8*)(Wlds + ((k * 8 + ks * 4 + nf) * 64 + lane) * 8);
                acc[nf] = __builtin_amdgcn_mfma_f32_16x16x32_f16(af, bfr, acc[nf], 0, 0, 0);
            }
        }

        if (k + 1 < K) {
#pragma unroll
            for (int g = 0; g < 2; ++g) { oy[g] = oy2[g]; ox[g] = ox2[g]; mm[g] = mm2[g]; }
        }
    }

    // ---- store: D row(px) = kg*4 + reg, col(o) = nf*16 + ml ----
    int hwb = hwwave + kg * 4;
#pragma unroll
    for (int nf = 0; nf < 4; ++nf) {
        size_t ob = ((size_t)(b * O + nf * 16 + ml)) * HXW + hwb;
        *(float4*)(out + ob) = __builtin_bit_cast(float4, acc[nf]);
    }
}

extern "C" void kernel_launch(void* const* d_in, const int* in_sizes, int n_in,
                              void* d_out, int out_size, void* d_ws, size_t ws_size,
                              hipStream_t stream) {
    const float* x      = (const float*)d_in[0];
    const float* offset = (const float*)d_in[1];
    const float* mask   = (const float*)d_in[2];
    const float* weight = (const float*)d_in[3];
    const float* bias   = (const float*)d_in[4];
    float* out = (float*)d_out;

    _Float16* wth = (_Float16*)d_ws;                              // 73728 B
    _Float16* xht = (_Float16*)((char*)d_ws + 73728);             // 8.39 MB
    size_t need = 73728 + (size_t)B * HXW * 64 * sizeof(_Float16);

    if (ws_size >= need) {
        int wth_blocks = (K * O * C + 255) / 256;                 // 144
        prep_kernel<<<XT_BLOCKS + wth_blocks, 256, 0, stream>>>(x, weight, xht, wth);
        mdcn_f16<<<256, 1024, 0, stream>>>(xht, offset, mask, wth, bias, out);
    } else {
        float* wt = (float*)d_ws;                                 // 147456 B (fallback)
        wt_kernel<<<(K * C * O + 255) / 256, 256, 0, stream>>>(weight, wt);
        mdcn_nchw<<<(B * HXW) / 256, 256, 0, stream>>>(x, offset, mask, wt, bias, out);
    }
}